// Round 11
// baseline (196.542 us; speedup 1.0000x reference)
//
#include <hip/hip_runtime.h>
#include <stdint.h>

#define IH 4096
#define IW 4096
#define OH 4090
#define OW 4090

#define TW 256            // output cols per block/wave
#define NW 4              // waves per block
#define RPW 16            // output rows per wave strip
#define RING 8            // wave-private LDS ring rows (slot = abs_row & 7)
#define LW 272            // floats per LDS row
#define YB (NW * RPW)     // 64 rows per block

typedef float v2f __attribute__((ext_vector_type(2)));
typedef __attribute__((address_space(1))) void gas_void;
typedef __attribute__((address_space(3))) void las_void;

// R7/R8/R9 (measured): three sync structures, identical 47.6us, nothing
// saturated. Surviving theories: (a) LDS pipe ~23us/CU serial component
// (issue + conflict cycles, serialized by per-row ds_read->FMA deps) --
// supported by R6->R7 scaling exactly with read count; (b) ~2.25TB/s HBM
// ceiling for this access mix. R10/R11 discriminates: cut LDS reads 3.6x by
// carrying the 6-row vertical overlap in REGISTERS across steps (RSTEP=2:
// 8-row window rolls by 2; lane's columns fixed -> carried rows stay valid;
// only 2 new rows/step read from LDS). mod-8 register window, 8 steps fully
// unrolled -> all indices compile-time (no scratch; win[r][10..11] dead ->
// ~80 live window VGPRs, fits the 128 cap). Ring 8 rows = 8.7KB/wave ->
// 34.8KB/block -> 4 blocks/CU = 16 waves/CU, 1024 blocks, single round.
// Zero barriers; R9's exact per-wave vmcnt ledger, loads staged 4 steps
// (~3500cy) ahead. Read-then-overwrite slot reuse fenced by lgkmcnt(0)
// before same-step STAGE (ds_read data in VGPRs first).
// R10 audit (container flake, no counters): ledger re-derived exact
// {16,20,24,28,24,20,16}; ring slots distinct; bounds exact; resubmitted.
// Prediction: conflicts 8.29M -> ~2.3M; T-LDS -> 33-38us; unchanged -> HBM.

__device__ __forceinline__ void stage_row(const float* __restrict__ x,
                                          int iy, int slot, int tile_x0,
                                          float* ring, int tx)
{
    iy = iy < IH ? iy : IH - 1;                       // safety clamp (never consumed)
    const float* gr = x + ((size_t)iy << 12);
    // Chunk 1: 64 lanes x 16B -> cols 0..255. tile_x0 <= 3834 -> c0 <= 4086:
    // always in-bounds, exact mapping (no clamp distortion).
    const int c0 = tile_x0 + 4 * tx;
    float* lp = ring + slot * LW;                     // wave-uniform LDS base
    __builtin_amdgcn_global_load_lds((gas_void*)(gr + c0), (las_void*)lp, 16, 0, 0);
    // Chunk 2: 8 lanes x 4B -> cols 256..263, per-float clamp; consumed cols
    // <= 261 map exactly (edge tile: tile_x0+261 = 4095).
    int c1 = tile_x0 + 256 + tx;
    c1 = c1 <= IW - 1 ? c1 : IW - 1;
    if (tx < 8)                                       // lanes 0..7 always active -> always issued
        __builtin_amdgcn_global_load_lds((gas_void*)(gr + c1), (las_void*)(lp + 256), 4, 0, 0);
}

#define READROW(W, SPTR) do {                                        \
    const float4 q0_ = *(const float4*)(SPTR);                       \
    const float4 q1_ = *(const float4*)((SPTR) + 4);                 \
    const float4 q2_ = *(const float4*)((SPTR) + 8);                 \
    (W)[0]=q0_.x; (W)[1]=q0_.y; (W)[2]=q0_.z;  (W)[3]=q0_.w;         \
    (W)[4]=q1_.x; (W)[5]=q1_.y; (W)[6]=q1_.z;  (W)[7]=q1_.w;         \
    (W)[8]=q2_.x; (W)[9]=q2_.y; (W)[10]=q2_.z; (W)[11]=q2_.w;        \
} while (0)

#define VMWAIT(N) do {                                               \
    asm volatile("s_waitcnt vmcnt(" #N ")" ::: "memory");            \
    __builtin_amdgcn_sched_barrier(0);                               \
} while (0)

#define LGKM0 do {                                                   \
    asm volatile("s_waitcnt lgkmcnt(0)" ::: "memory");               \
    __builtin_amdgcn_sched_barrier(0);                               \
} while (0)

// Read the two NEW rows for step S (abs rows 2S+6, 2S+7) into their window
// slots. 6 x ds_read_b128 (16B lane stride; b64 would be 8-way conflicted).
#define READ2(S) do {                                                \
    READROW(win[(2*(S)+6) & 7], ring + ((2*(S)+6) & 7) * LW + lx0);  \
    READROW(win[(2*(S)+7) & 7], ring + ((2*(S)+7) & 7) * LW + lx0);  \
} while (0)

// Stage rows 2S+14, 2S+15 (consumed at step S+4) into the slots just freed
// by READ2(S). MUST be issued after LGKM0 (ds_read data already in VGPRs).
#define STAGE2(S) do {                                               \
    stage_row(x, strip_y0 + 2*(S) + 14, (2*(S)+14) & 7, tile_x0, ring, tx); \
    stage_row(x, strip_y0 + 2*(S) + 15, (2*(S)+15) & 7, tile_x0, ring, tx); \
    __builtin_amdgcn_sched_barrier(0);                               \
} while (0)

// 2 output rows x 4 cols; input row (2S+d+ky) lives in win[(2S+d+ky)&7].
#define COMP2(S, A0, A1) do {                                        \
    _Pragma("unroll") for (int c = 0; c < 4; ++c) { (A0)[c] = b; (A1)[c] = b; } \
    _Pragma("unroll") for (int ky = 0; ky < 7; ++ky) {               \
        _Pragma("unroll") for (int kx = 0; kx < 7; ++kx) {           \
            const float ww_ = wt[ky * 7 + kx];                       \
            _Pragma("unroll") for (int c = 0; c < 4; ++c) {          \
                (A0)[c] += ww_ * win[(2*(S)+ky)   & 7][kx + c];      \
                (A1)[c] += ww_ * win[(2*(S)+1+ky) & 7][kx + c];      \
            } } } } while (0)

// Exactly 4 inline-asm dwordx2 temporal stores per step (ledger-exact; R3
// lesson: nt stores in flight never combine -> temporal only).
#define ST2(S, A0, A1) do {                                          \
    float* o0_ = out + (size_t)(strip_y0 + 2*(S))     * OW + ox0;    \
    float* o1_ = out + (size_t)(strip_y0 + 2*(S) + 1) * OW + ox0;    \
    v2f p0_ = { (A0)[0], (A0)[1] }, p1_ = { (A0)[2], (A0)[3] };      \
    v2f p2_ = { (A1)[0], (A1)[1] }, p3_ = { (A1)[2], (A1)[3] };      \
    asm volatile("global_store_dwordx2 %0, %1, off" :: "v"(o0_),     "v"(p0_)); \
    asm volatile("global_store_dwordx2 %0, %1, off" :: "v"(o0_ + 2), "v"(p1_)); \
    asm volatile("global_store_dwordx2 %0, %1, off" :: "v"(o1_),     "v"(p2_)); \
    asm volatile("global_store_dwordx2 %0, %1, off" :: "v"(o1_ + 2), "v"(p3_)); \
} while (0)

__global__ __launch_bounds__(256, 4) void conv7x7_regwin(
    const float* __restrict__ x,
    const float* __restrict__ w,
    const float* __restrict__ bias,
    float* __restrict__ out)
{
    __shared__ float smem[NW * RING * LW];            // 34,816 B -> 4 blocks/CU

    const int tid = threadIdx.x;
    const int tx  = tid & 63;
    const int wv  = tid >> 6;                         // 0..3

    // Shift-clamped tile origins (edge overlap recomputed; benign identical
    // double-stores) -> guard-free epilogue, exact uniform vmem counts.
    int tile_x0 = blockIdx.x * TW;
    if (tile_x0 > OW - TW) tile_x0 = OW - TW;         // 3834 (even -> 8B store align)
    int y0 = blockIdx.y * YB;
    if (y0 > OH - YB) y0 = OH - YB;                   // 4026; max staged row 4074+21=4095 exact

    const int strip_y0 = y0 + RPW * wv;               // wave-private 16-row strip
    float* ring = smem + wv * (RING * LW);            // wave-private ring

    // Wave-uniform weights -> SGPRs.
    float wt[49];
#pragma unroll
    for (int k = 0; k < 49; ++k) wt[k] = w[k];
    const float b = bias[0];

    const int lx0 = 4 * tx;
    const int ox0 = tile_x0 + lx0;

    // ---- Prologue: stage rows 0..7 (16 loads), drain, read all 8 into the
    // register window, then stage-ahead rows 8..13 into freed slots 0..5.
#pragma unroll
    for (int r = 0; r < 8; ++r)
        stage_row(x, strip_y0 + r, r, tile_x0, ring, tx);
    VMWAIT(0);

    float win[8][12];                                 // rolling mod-8 row window
#pragma unroll
    for (int r = 0; r < 8; ++r)
        READROW(win[r], ring + r * LW + lx0);
    LGKM0;                                            // reads done -> slots reusable

#pragma unroll
    for (int r = 8; r < 14; ++r)                      // A-stages: 12 loads outstanding
        stage_row(x, strip_y0 + r, r & 7, tile_x0, ring, tx);
    __builtin_amdgcn_sched_barrier(0);

    float a0[4], a1[4];

    // ---- Step 0: window complete from prologue; no wait, no read.
    COMP2(0, a0, a1);
    LGKM0;                                            // uniform ordering (cheap)
    STAGE2(0);                                        // rows 14,15 -> slots 6,7
    ST2(0, a0, a1);

    // Ledger (oldest->newest) before each step's wait; target = that step's
    // rows' stage, N = count of newer vmem ops (stages 4/pair, stores 4/step).
    // s1: newer = A(rows10..13)=8, S0=4, ST0=4        -> 16
    VMWAIT(16); READ2(1); COMP2(1, a0, a1); LGKM0; STAGE2(1); ST2(1, a0, a1);
    // s2: newer = A(rows12,13)=4, S0,ST0,S1,ST1       -> 20
    VMWAIT(20); READ2(2); COMP2(2, a0, a1); LGKM0; STAGE2(2); ST2(2, a0, a1);
    // s3: newer = S0,ST0,S1,ST1,S2,ST2                -> 24
    VMWAIT(24); READ2(3); COMP2(3, a0, a1); LGKM0; STAGE2(3); ST2(3, a0, a1);
    // s4: newer = ST0,S1,ST1,S2,ST2,S3,ST3            -> 28
    VMWAIT(28); READ2(4); COMP2(4, a0, a1); LGKM0; ST2(4, a0, a1);
    // s5: newer = ST1,S2,ST2,S3,ST3,ST4               -> 24
    VMWAIT(24); READ2(5); COMP2(5, a0, a1); LGKM0; ST2(5, a0, a1);
    // s6: newer = ST2,S3,ST3,ST4,ST5                  -> 20
    VMWAIT(20); READ2(6); COMP2(6, a0, a1); LGKM0; ST2(6, a0, a1);
    // s7: newer = ST3,ST4,ST5,ST6                     -> 16
    VMWAIT(16); READ2(7); COMP2(7, a0, a1); LGKM0; ST2(7, a0, a1);
}

extern "C" void kernel_launch(void* const* d_in, const int* in_sizes, int n_in,
                              void* d_out, int out_size, void* d_ws, size_t ws_size,
                              hipStream_t stream) {
    const float* x    = (const float*)d_in[0];
    const float* w    = (const float*)d_in[1];
    const float* bias = (const float*)d_in[2];
    float* out        = (float*)d_out;

    // 16 x-tiles x 64 y-tiles = 1024 blocks = exactly 4/CU resident
    // (34.8KB LDS, VGPR capped 128 by launch_bounds) = 16 waves/CU,
    // zero barriers, single round, no tail.
    dim3 grid((OW + TW - 1) / TW, 4096 / YB);
    conv7x7_regwin<<<grid, dim3(256), 0, stream>>>(x, w, bias, out);
}